// Round 9
// baseline (894.425 us; speedup 1.0000x reference)
//
#include <hip/hip_runtime.h>

constexpr int kNodes = 1000000;
constexpr int kEdges = 32000000;

// ---------------- Tile-sorted scatter path (id-record + qtab) ----------------
// 256 buckets x 4096 nodes. Record u32 = (node&4095)<<20 | other_id(20b).
// Scatter does NO value gathers -- it is a pure integer counting sort:
// coalesced edge loads -> rank atomic r=atomicAdd(cnt[b]) -> slab[b*72+r]
// -> per-bucket arena segment (16B-aligned) via one gcur atomicAdd/bucket
// -> int4 flush. P(seg>72 slots) ~ 1e-11 -> overflow list + exact fixup.
// Consumer gathers the value: qtab[other] = q16|deg_bit (4 MB, L2-resident;
// qtab[j>=1M] = 0 so PADREC=0xFFFFFFFF contributes nothing, branchlessly),
// one LDS atomic per record into a 4096-entry per-bucket table.
// R6 calibration: direct global atomics = 2.4 ms for 64M -- sort is mandatory.
// R1..R8 calibration: accum ~300 us regardless of access pattern; this round
// moves the 64M gathers into accum to price that bound (accum will top the
// profile -> counters next round).
constexpr int NB = 256;
constexpr int BSHIFT = 12;
constexpr int BNODES = 4096;
constexpr int NBUSED = (kNodes + BNODES - 1) / BNODES;   // 245
constexpr int EPT = 4096;                 // edges per tile
constexpr int TILES = (kEdges + EPT - 1) / EPT;          // 7813
constexpr int SLOT = 72;                  // slab slots/bucket (72%32=8: low conflict)
constexpr int GP = SLOT / 4;              // int4 groups per slab (18)
constexpr int CAP = 284672;               // per-bucket arena capacity (mult 4), ~20 sigma
constexpr int SPLIT = 2;
constexpr unsigned PADREC = 0xFFFFFFFFu;  // other=0xFFFFF -> qtab entry 0
constexpr unsigned OVFCAP = 8192;
constexpr int QTABN = 1 << 20;            // qtab entries (pow2, covers 20-bit field)

constexpr size_t kArenaBytes = (size_t)NBUSED * CAP * 4;   // ~279 MB
constexpr size_t kCurOff    = kArenaBytes;
constexpr size_t kCurBytes  = (size_t)NB * 64 + 64;        // strided cursors + ovfcnt
constexpr size_t kAccOff    = kCurOff + kCurBytes;
constexpr size_t kAccBytes  = (size_t)SPLIT * kNodes * 4;  // 8 MB
constexpr size_t kQtabOff   = kAccOff + kAccBytes;
constexpr size_t kQtabBytes = (size_t)QTABN * 4;           // 4 MB
constexpr size_t kOvfOff    = kQtabOff + kQtabBytes;
constexpr size_t kOvfBytes  = (size_t)OVFCAP * 8;          // 64 KB
constexpr size_t kWsNeeded  = kOvfOff + kOvfBytes;         // ~291 MB

// qtab[j] = q16(orc[j]) | 0x1000000 (deg bit) for j < kNodes, else 0.
__global__ __launch_bounds__(256) void qtab_build(
        const float* __restrict__ orc, unsigned* __restrict__ qtab,
        unsigned* __restrict__ gcur) {
    if (blockIdx.x == 0) {
        if (threadIdx.x < NB) gcur[threadIdx.x * 16] = 0u;
        if (threadIdx.x == 0) gcur[NB * 16] = 0u;       // overflow counter
    }
    const int i = (blockIdx.x * 256 + threadIdx.x) * 4;
    if (i < kNodes) {                                   // kNodes % 4 == 0
        const float4 v = *reinterpret_cast<const float4*>(orc + i);
        unsigned q0 = __float2uint_rn((v.x + 1.0f) * 32768.0f);
        unsigned q1 = __float2uint_rn((v.y + 1.0f) * 32768.0f);
        unsigned q2 = __float2uint_rn((v.z + 1.0f) * 32768.0f);
        unsigned q3 = __float2uint_rn((v.w + 1.0f) * 32768.0f);
        uint4 q;
        q.x = (q0 > 65535u ? 65535u : q0) | 0x1000000u;
        q.y = (q1 > 65535u ? 65535u : q1) | 0x1000000u;
        q.z = (q2 > 65535u ? 65535u : q2) | 0x1000000u;
        q.w = (q3 > 65535u ? 65535u : q3) | 0x1000000u;
        *reinterpret_cast<uint4*>(qtab + i) = q;
    } else if (i < QTABN) {
        uint4 z; z.x = z.y = z.z = z.w = 0u;
        *reinterpret_cast<uint4*>(qtab + i) = z;
    }
}

__global__ __launch_bounds__(1024) void scatter_sort(
        const int* __restrict__ ei, unsigned* __restrict__ arena,
        unsigned* __restrict__ gcur, unsigned long long* __restrict__ ovf) {
    __shared__ alignas(16) unsigned slab[NB * SLOT];   // 72 KB
    __shared__ unsigned cnt[NB];                       // rank cursors
    __shared__ unsigned pcs[NB];                       // padded counts
    __shared__ unsigned dstadd[NB];                    // arena dst base
    const int tid = threadIdx.x;
    const int t = blockIdx.x;
    const int e0 = t * EPT;
    const int ne = min(EPT, kEdges - e0);   // 4096; last tile 2048
    const int k4 = tid * 4;

    if (tid < NB) cnt[tid] = 0u;
    __syncthreads();

    // phase 1: coalesced edge loads -> rank + slab store. No value gathers.
    if (k4 < ne) {
        const int4 s4 = *reinterpret_cast<const int4*>(ei + e0 + k4);
        const int4 d4 = *reinterpret_cast<const int4*>(ei + kEdges + e0 + k4);
        #define RANK1(N, O) { \
            const unsigned b_ = (unsigned)(N) >> BSHIFT; \
            const unsigned r_ = atomicAdd(&cnt[b_], 1u); \
            if (r_ < (unsigned)SLOT) { \
                slab[b_ * SLOT + r_] = \
                    (((unsigned)(N) & (BNODES - 1)) << 20) | (unsigned)(O); \
            } else { \
                const unsigned oi_ = atomicAdd(&gcur[NB * 16], 1u); \
                if (oi_ < OVFCAP) \
                    ovf[oi_] = ((unsigned long long)(unsigned)(N) << 32) | \
                               (unsigned)(O); \
            } }
        RANK1(s4.x, d4.x) RANK1(s4.y, d4.y) RANK1(s4.z, d4.z) RANK1(s4.w, d4.w)
        RANK1(d4.x, s4.x) RANK1(d4.y, s4.y) RANK1(d4.z, s4.z) RANK1(d4.w, s4.w)
        #undef RANK1
    }
    __syncthreads();

    // phase 2: per-bucket arena allocation + tail pad (tid<NB lanes only)
    if (tid < NB) {
        unsigned c = cnt[tid];
        c = c > (unsigned)SLOT ? (unsigned)SLOT : c;
        const unsigned pc = (c + 3u) & ~3u;
        pcs[tid] = pc;
        unsigned g = atomicAdd(&gcur[tid * 16], pc);
        if (g + pc > (unsigned)CAP) g = CAP - pc;   // ~20-sigma safety clamp
        dstadd[tid] = (unsigned)tid * CAP + g;
        for (unsigned j = c; j < pc; ++j) slab[tid * SLOT + j] = PADREC;
    }
    __syncthreads();

    // phase 3: int4 flush of live groups to 16B-aligned arena positions
    for (int k = tid; k < NB * GP; k += 1024) {
        const int b = k / GP;
        const int g4 = (k - b * GP) * 4;
        if ((unsigned)g4 < pcs[b]) {
            *reinterpret_cast<int4*>(arena + dstadd[b] + g4) =
                *reinterpret_cast<const int4*>(slab + b * SLOT + g4);
        }
    }
}

__global__ __launch_bounds__(1024) void bucket_accum(
        const unsigned* __restrict__ arena, const unsigned* __restrict__ gcur,
        const unsigned* __restrict__ qtab, unsigned* __restrict__ acc) {
    __shared__ unsigned lacc[BNODES];             // 16 KB
    const int tid = threadIdx.x;
    const int b = blockIdx.x >> 1;
    const int half = blockIdx.x & 1;
    for (int k = tid; k < BNODES; k += 1024) lacc[k] = 0u;
    __syncthreads();
    unsigned len = gcur[b * 16];                  // padded records, mult of 4
    len = len > (unsigned)CAP ? (unsigned)CAP : len;
    const unsigned h = (len >> 1) & ~3u;
    const unsigned lo4 = (half ? h : 0u) >> 2;
    const unsigned hi4 = (half ? len : h) >> 2;
    const uint4* __restrict__ p =
        reinterpret_cast<const uint4*>(arena + (size_t)b * CAP);
    // paired segment loads; 8 independent qtab gathers in flight per iter
    unsigned i = lo4 + tid;
    for (; i + 1024 < hi4; i += 2048) {
        const uint4 v0 = p[i];
        const uint4 v1 = p[i + 1024];
        const unsigned q0 = qtab[v0.x & 0xFFFFFu];
        const unsigned q1 = qtab[v0.y & 0xFFFFFu];
        const unsigned q2 = qtab[v0.z & 0xFFFFFu];
        const unsigned q3 = qtab[v0.w & 0xFFFFFu];
        const unsigned q4 = qtab[v1.x & 0xFFFFFu];
        const unsigned q5 = qtab[v1.y & 0xFFFFFu];
        const unsigned q6 = qtab[v1.z & 0xFFFFFu];
        const unsigned q7 = qtab[v1.w & 0xFFFFFu];
        atomicAdd(&lacc[v0.x >> 20], q0);
        atomicAdd(&lacc[v0.y >> 20], q1);
        atomicAdd(&lacc[v0.z >> 20], q2);
        atomicAdd(&lacc[v0.w >> 20], q3);
        atomicAdd(&lacc[v1.x >> 20], q4);
        atomicAdd(&lacc[v1.y >> 20], q5);
        atomicAdd(&lacc[v1.z >> 20], q6);
        atomicAdd(&lacc[v1.w >> 20], q7);
    }
    if (i < hi4) {
        const uint4 v = p[i];
        atomicAdd(&lacc[v.x >> 20], qtab[v.x & 0xFFFFFu]);
        atomicAdd(&lacc[v.y >> 20], qtab[v.y & 0xFFFFFu]);
        atomicAdd(&lacc[v.z >> 20], qtab[v.z & 0xFFFFFu]);
        atomicAdd(&lacc[v.w >> 20], qtab[v.w & 0xFFFFFu]);
    }
    __syncthreads();
    const int base = b << BSHIFT;
    unsigned* __restrict__ dst = acc + (size_t)half * kNodes;
    for (int k = tid; k < BNODES; k += 1024) {
        const int nn = base + k;
        if (nn < kNodes) dst[nn] = lacc[k];
    }
}

// Exact fixup for the (statistically ~0) slab-overflow records.
__global__ __launch_bounds__(256) void ovf_fix(
        const unsigned long long* __restrict__ ovf,
        const unsigned* __restrict__ gcur, const unsigned* __restrict__ qtab,
        unsigned* __restrict__ acc) {
    unsigned n = gcur[NB * 16];
    n = n > OVFCAP ? OVFCAP : n;
    for (unsigned i = threadIdx.x; i < n; i += 256) {
        const unsigned long long v = ovf[i];
        atomicAdd(&acc[(unsigned)(v >> 32)], qtab[(unsigned)v & 0xFFFFFu]);
    }
}

// ---------------- Fallback (atomic u64) path ----------------
constexpr float kScale = 1048576.0f;           // 2^20
constexpr float kInvScale = 1.0f / 1048576.0f;
constexpr long long kBias = 1ll << 36;

__global__ __launch_bounds__(256) void zero_acc(unsigned long long* __restrict__ acc) {
    int i = blockIdx.x * 256 + threadIdx.x;
    if (i < kNodes) acc[i] = 0ull;
}

__global__ __launch_bounds__(256) void edge_kernel(
        const int* __restrict__ ei,
        const float* __restrict__ orc,
        unsigned long long* __restrict__ acc) {
    int t = blockIdx.x * 256 + threadIdx.x;
    int e0 = t * 4;
    if (e0 >= kEdges) return;
    const int4 s4 = *reinterpret_cast<const int4*>(ei + e0);
    const int4 d4 = *reinterpret_cast<const int4*>(ei + kEdges + e0);
    const int ss[4] = {s4.x, s4.y, s4.z, s4.w};
    const int dd[4] = {d4.x, d4.y, d4.z, d4.w};
    #pragma unroll
    for (int k = 0; k < 4; ++k) {
        const float os = orc[ss[k]];
        const float od = orc[dd[k]];
        const unsigned long long ps =
            (1ull << 48) + (unsigned long long)(kBias + (long long)__float2ll_rn(od * kScale));
        const unsigned long long pd =
            (1ull << 48) + (unsigned long long)(kBias + (long long)__float2ll_rn(os * kScale));
        atomicAdd(&acc[ss[k]], ps);
        atomicAdd(&acc[dd[k]], pd);
    }
}

// ---------------- Node phase ----------------
// MODE 0: u64 cell, deg<<48 | biased 2^20 fixed sum.
// MODE 3: two u32 partials, each deg<<24 | sum(q16).
template <int MODE>
__global__ __launch_bounds__(256) void node_kernel(
        const float* __restrict__ orc,
        const unsigned long long* __restrict__ acc64,
        const unsigned* __restrict__ acc32,
        const float* __restrict__ W1, const float* __restrict__ b1,
        const float* __restrict__ W2, const float* __restrict__ b2,
        const float* __restrict__ gamma, const float* __restrict__ beta,
        float* __restrict__ out) {
    const int i = blockIdx.x * 256 + threadIdx.x;
    if (i >= kNodes) return;

    const float x0 = orc[i];
    float nb;
    if (MODE == 0) {
        const unsigned long long p = acc64[i];
        const unsigned deg = (unsigned)(p >> 48);
        const long long sf = (long long)(p & ((1ull << 48) - 1)) - (long long)deg * kBias;
        const float s = (float)sf * kInvScale;
        nb = (deg > 0) ? s / (float)deg : 0.0f;
    } else {
        const unsigned p0 = acc32[i];
        const unsigned p1 = acc32[kNodes + i];
        const unsigned deg = (p0 >> 24) + (p1 >> 24);
        const unsigned sumq = (p0 & 0xFFFFFFu) + (p1 & 0xFFFFFFu);
        nb = (deg > 0)
            ? ((float)sumq * (1.0f / 32768.0f) / (float)deg - 1.0f) : 0.0f;
    }

    constexpr float kPi = 3.14159265358979323846f;
    float Phi[16];
    const float n0 = __saturatef((x0 + 1.0f) * 0.5f);
    const float n1 = __saturatef((nb + 1.0f) * 0.5f);
    #pragma unroll
    for (int k = 0; k < 4; ++k) {
        const float a0 = n0 * (float)(k + 1) * kPi;
        const float a1 = n1 * (float)(k + 1) * kPi;
        Phi[2 * k]     = __sinf(a0);
        Phi[2 * k + 1] = __cosf(a0);
        Phi[8 + 2 * k]     = __sinf(a1);
        Phi[8 + 2 * k + 1] = __cosf(a1);
    }

    float y[16];
    #pragma unroll
    for (int d = 0; d < 16; ++d) y[d] = b2[d];
    #pragma unroll
    for (int j = 0; j < 32; ++j) {
        float a = b1[j];
        #pragma unroll
        for (int d = 0; d < 16; ++d) a = fmaf(Phi[d], W1[j * 16 + d], a);
        a = fmaxf(a, 0.0f);
        #pragma unroll
        for (int d = 0; d < 16; ++d) y[d] = fmaf(a, W2[d * 32 + j], y[d]);
    }

    float mu = 0.0f;
    #pragma unroll
    for (int d = 0; d < 16; ++d) mu += y[d];
    mu *= (1.0f / 16.0f);
    float var = 0.0f;
    #pragma unroll
    for (int d = 0; d < 16; ++d) { const float t = y[d] - mu; var = fmaf(t, t, var); }
    var *= (1.0f / 16.0f);
    const float inv = rsqrtf(var + 1e-5f);

    float4* o4 = reinterpret_cast<float4*>(out + (size_t)i * 16);
    #pragma unroll
    for (int q = 0; q < 4; ++q) {
        float4 o;
        o.x = (y[4 * q + 0] - mu) * inv * gamma[4 * q + 0] + beta[4 * q + 0] + Phi[4 * q + 0];
        o.y = (y[4 * q + 1] - mu) * inv * gamma[4 * q + 1] + beta[4 * q + 1] + Phi[4 * q + 1];
        o.z = (y[4 * q + 2] - mu) * inv * gamma[4 * q + 2] + beta[4 * q + 2] + Phi[4 * q + 2];
        o.w = (y[4 * q + 3] - mu) * inv * gamma[4 * q + 3] + beta[4 * q + 3] + Phi[4 * q + 3];
        o4[q] = o;
    }
}

extern "C" void kernel_launch(void* const* d_in, const int* in_sizes, int n_in,
                              void* d_out, int out_size, void* d_ws, size_t ws_size,
                              hipStream_t stream) {
    const float* orc   = (const float*)d_in[0];
    const int*   ei    = (const int*)d_in[1];
    const float* W1    = (const float*)d_in[2];
    const float* b1    = (const float*)d_in[3];
    const float* W2    = (const float*)d_in[4];
    const float* b2    = (const float*)d_in[5];
    const float* gamma = (const float*)d_in[6];
    const float* beta  = (const float*)d_in[7];
    float* out = (float*)d_out;
    char* ws = (char*)d_ws;

    if (ws_size >= kWsNeeded) {
        unsigned* arena = (unsigned*)ws;
        unsigned* gcur = (unsigned*)(ws + kCurOff);
        unsigned* acc = (unsigned*)(ws + kAccOff);
        unsigned* qtab = (unsigned*)(ws + kQtabOff);
        unsigned long long* ovf = (unsigned long long*)(ws + kOvfOff);
        qtab_build<<<QTABN / 4 / 256, 256, 0, stream>>>(orc, qtab, gcur);
        scatter_sort<<<TILES, 1024, 0, stream>>>(ei, arena, gcur, ovf);
        bucket_accum<<<NBUSED * SPLIT, 1024, 0, stream>>>(arena, gcur, qtab, acc);
        ovf_fix<<<1, 256, 0, stream>>>(ovf, gcur, qtab, acc);
        node_kernel<3><<<(kNodes + 255) / 256, 256, 0, stream>>>(
            orc, nullptr, acc, W1, b1, W2, b2, gamma, beta, out);
    } else {
        unsigned long long* acc = (unsigned long long*)ws;  // 8 MB
        zero_acc<<<(kNodes + 255) / 256, 256, 0, stream>>>(acc);
        edge_kernel<<<(kEdges / 4 + 255) / 256, 256, 0, stream>>>(ei, orc, acc);
        node_kernel<0><<<(kNodes + 255) / 256, 256, 0, stream>>>(
            orc, acc, nullptr, W1, b1, W2, b2, gamma, beta, out);
    }
}